// Round 1
// baseline (203.864 us; speedup 1.0000x reference)
//
#include <hip/hip_runtime.h>

// Discounted cumulative return: y[t] = r[t] + a[t]*y[t+1], a[t] = terminal[t] ? 0 : 0.99
// Reverse affine-scan via 3-pass reduce-then-scan (no cross-block atomics).

constexpr int   TPB  = 256;
constexpr int   IPT  = 16;            // elements per thread (64B line per lane)
constexpr int   TILE = TPB * IPT;     // 4096 elements per block
constexpr float DISC = 0.99f;

// Inclusive block "scan" of affine functions in scan order (thread 0 = applied first).
// Composition: result_t = F_t o F_{t-1} o ... o F_0   (F(x) = A*x + B)
__device__ __forceinline__ void block_scan_inc(float& A, float& B,
                                               float* sA, float* sB, int t) {
    sA[t] = A; sB[t] = B;
    __syncthreads();
    #pragma unroll
    for (int off = 1; off < TPB; off <<= 1) {
        float pa = 1.f, pb = 0.f;
        if (t >= off) { pa = sA[t - off]; pb = sB[t - off]; }
        __syncthreads();
        B = A * pb + B;   // self o prev  = (A*pa, A*pb + B)
        A = A * pa;
        sA[t] = A; sB[t] = B;
        __syncthreads();
    }
}

// Load IPT elements (reward + discount factor) for this thread's chunk.
__device__ __forceinline__ void load_chunk(const int* __restrict__ term,
                                           const float* __restrict__ rew,
                                           long long base, long long T,
                                           float* r, float* a, bool fast) {
    if (fast) {
        #pragma unroll
        for (int q = 0; q < IPT / 4; ++q) {
            float4 rv = ((const float4*)(rew + base))[q];
            int4   tv = ((const int4*)(term + base))[q];
            r[4*q+0] = rv.x; r[4*q+1] = rv.y; r[4*q+2] = rv.z; r[4*q+3] = rv.w;
            a[4*q+0] = tv.x ? 0.f : DISC;
            a[4*q+1] = tv.y ? 0.f : DISC;
            a[4*q+2] = tv.z ? 0.f : DISC;
            a[4*q+3] = tv.w ? 0.f : DISC;
        }
    } else {
        #pragma unroll
        for (int k = 0; k < IPT; ++k) {
            long long i = base + k;
            if (i < T) { r[k] = rew[i]; a[k] = term[i] ? 0.f : DISC; }
            else       { r[k] = 0.f;   a[k] = 1.f; }   // identity padding
        }
    }
}

// K1: per-block affine aggregate (A_g, B_g) mapping y[tileEnd] -> y[tileBase].
__global__ __launch_bounds__(TPB) void k_agg(const int* __restrict__ term,
                                             const float* __restrict__ rew,
                                             float* __restrict__ aggA,
                                             float* __restrict__ aggB,
                                             long long T) {
    __shared__ float sA[TPB], sB[TPB];
    const int t = threadIdx.x;
    const long long tileBase = (long long)blockIdx.x * TILE;
    // thread t covers DESCENDING index chunks: t=0 gets the highest indices
    const long long base = tileBase + (long long)(TPB - 1 - t) * IPT;

    float r[IPT], a[IPT];
    const bool fast = (base + IPT <= T);
    load_chunk(term, rew, base, T, r, a, fast);

    // local compose, high index -> low index: F = f_k o F
    float A = 1.f, B = 0.f;
    #pragma unroll
    for (int k = IPT - 1; k >= 0; --k) { B = a[k] * B + r[k]; A = a[k] * A; }

    block_scan_inc(A, B, sA, sB, t);

    if (t == TPB - 1) { aggA[blockIdx.x] = A; aggB[blockIdx.x] = B; }
}

// K2: single block; for each tile g emit y_in[g] = (F_{g+1} o ... o F_{N-1})(0).
__global__ __launch_bounds__(TPB) void k_scan(const float* __restrict__ aggA,
                                              const float* __restrict__ aggB,
                                              float* __restrict__ yin,
                                              int numTiles) {
    __shared__ float sA[TPB], sB[TPB];
    const int t = threadIdx.x;
    const int cpt = (numTiles + TPB - 1) / TPB;
    const int hi = numTiles - 1 - t * cpt;   // thread t covers g in [hi-cpt+1, hi], descending

    float A = 1.f, B = 0.f;
    for (int k = 0; k < cpt; ++k) {
        int g = hi - k;
        if (g >= 0) {
            float ag = aggA[g], bg = aggB[g];
            B = ag * B + bg; A = ag * A;
        }
    }

    block_scan_inc(A, B, sA, sB, t);

    float EA = 1.f, EB = 0.f;            // exclusive: everything at higher g
    if (t > 0) { EA = sA[t - 1]; EB = sB[t - 1]; }
    for (int k = 0; k < cpt; ++k) {
        int g = hi - k;
        if (g >= 0) {
            yin[g] = EB;                 // value entering tile g from above
            float ag = aggA[g], bg = aggB[g];
            EB = ag * EB + bg; EA = ag * EA;
        }
    }
}

// K3: re-read inputs, apply block prefix, write outputs.
__global__ __launch_bounds__(TPB) void k_apply(const int* __restrict__ term,
                                               const float* __restrict__ rew,
                                               const float* __restrict__ yin,
                                               float* __restrict__ out,
                                               long long T) {
    __shared__ float sA[TPB], sB[TPB];
    const int t = threadIdx.x;
    const long long tileBase = (long long)blockIdx.x * TILE;
    const long long base = tileBase + (long long)(TPB - 1 - t) * IPT;

    float r[IPT], a[IPT];
    const bool fast = (base + IPT <= T);
    load_chunk(term, rew, base, T, r, a, fast);

    float A = 1.f, B = 0.f;
    #pragma unroll
    for (int k = IPT - 1; k >= 0; --k) { B = a[k] * B + r[k]; A = a[k] * A; }

    block_scan_inc(A, B, sA, sB, t);

    float EA = 1.f, EB = 0.f;            // exclusive over threads 0..t-1 (higher indices)
    if (t > 0) { EA = sA[t - 1]; EB = sB[t - 1]; }

    const float yblk = yin[blockIdx.x];  // y at tileBase + TILE
    float y = EA * yblk + EB;            // y at base + IPT

    float yv[IPT];
    #pragma unroll
    for (int k = IPT - 1; k >= 0; --k) { y = a[k] * y + r[k]; yv[k] = y; }

    if (fast) {
        #pragma unroll
        for (int q = 0; q < IPT / 4; ++q) {
            ((float4*)(out + base))[q] =
                make_float4(yv[4*q+0], yv[4*q+1], yv[4*q+2], yv[4*q+3]);
        }
    } else {
        #pragma unroll
        for (int k = 0; k < IPT; ++k) {
            long long i = base + k;
            if (i < T) out[i] = yv[k];
        }
    }
}

extern "C" void kernel_launch(void* const* d_in, const int* in_sizes, int n_in,
                              void* d_out, int out_size, void* d_ws, size_t ws_size,
                              hipStream_t stream) {
    const int*   term = (const int*)d_in[0];    // terminal (bool -> int32 per harness)
    const float* rew  = (const float*)d_in[1];  // reward fp32
    float*       out  = (float*)d_out;

    const long long T = (long long)in_sizes[1];
    const int numTiles = (int)((T + TILE - 1) / TILE);

    float* aggA = (float*)d_ws;
    float* aggB = aggA + numTiles;
    float* yin  = aggB + numTiles;

    k_agg  <<<numTiles, TPB, 0, stream>>>(term, rew, aggA, aggB, T);
    k_scan <<<1,        TPB, 0, stream>>>(aggA, aggB, yin, numTiles);
    k_apply<<<numTiles, TPB, 0, stream>>>(term, rew, yin, out, T);
}